// Round 1
// baseline (174.093 us; speedup 1.0000x reference)
//
#include <hip/hip_runtime.h>

// AMPS chain kernel, MI355X/gfx950.
//
// Structure: for each n in [0,1022], batch b in [0,8):
//   v = e0^T ; for m in 0..n: v = v @ tri_up[n(n+1)/2+m, :, :, sel(b,m)]
//   sel(b,m) = 0 if data[b][m]==1 else 1  (data is exactly {0.0,1.0})
//   out[n+1,b,p] = v . diag[n+1,:,p]; 2-way log-softmax; pick by data[b][n+1];
//   sum over positions (pos 0 term = log_softmax(diag[0,0,:]) picked by data[b][0]).
//
// One wave (64 threads) per chain n. Lanes (b = lane>>2 & 7, r = lane&3):
// lane holds v[r] for batch b; DPP quad_perm broadcasts v[l] for the 4-term dot
// (v_mul/v_fmac with DPP src -> ~4 VALU per step, no LDS in the dep chain).
// Tri loads: 4 x dword per step (stride 32B, one 128B line per step, batches
// broadcast). Register double-buffer: tri 1 block (16 steps) ahead, data 2 ahead.
// Partials to d_ws[block][batch]; 1-block reduce kernel sums 1024x8 -> d_out[8].

#define NPOS   1024
#define BATCH  8
#define UNROLL 16

template<int l>
__device__ __forceinline__ float qb(float x) {
    // quad_perm broadcast lane l within each group of 4 lanes
    constexpr int ctrl = l * 0x55;           // l | l<<2 | l<<4 | l<<6
    return __int_as_float(__builtin_amdgcn_update_dpp(
        __float_as_int(x), __float_as_int(x), ctrl, 0xF, 0xF, false));
}

template<int ctrl>
__device__ __forceinline__ float qperm(float x) {
    return __int_as_float(__builtin_amdgcn_update_dpp(
        __float_as_int(x), __float_as_int(x), ctrl, 0xF, 0xF, false));
}

__global__ __launch_bounds__(64) void amps_chain(
        const float* __restrict__ data,   // (8, 1024)
        const float* __restrict__ tri,    // (523776, 4, 4, 2)
        const float* __restrict__ diag,   // (1024, 4, 2)
        float* __restrict__ ws)           // (1024, 8) partial sums
{
    const int bx   = blockIdx.x;
    const int lane = threadIdx.x;
    const int b    = (lane >> 2) & 7;     // lanes 32..63 duplicate batches (harmless)
    const int r    = lane & 3;

    if (bx == NPOS - 1) {
        // position-0 term: logits = diag[0,0,:], same for all batches
        if (lane < BATCH) {
            float o0 = diag[0], o1 = diag[1];
            float mx  = fmaxf(o0, o1);
            float lse = mx + __logf(__expf(o0 - mx) + __expf(o1 - mx));
            float d0  = data[lane * NPOS];
            ws[(NPOS - 1) * BATCH + lane] = ((d0 == 1.0f) ? o0 : o1) - lse;
        }
        return;
    }

    // load-balance pairing: blocks bx and bx+512 (likely same CU) get chains
    // n = j and n = 1022 - j, so per-CU byte totals are ~equal.
    const int n     = (bx < 512) ? bx : (1534 - bx);   // chain index 0..1022
    const int steps = n + 1;
    const int nfull = steps / UNROLL;

    const float* __restrict__ tp = tri + (size_t)n * (n + 1) / 2 * 32;
    const float* __restrict__ dp = data + b * NPOS;

    float v = (r == 0) ? 1.0f : 0.0f;     // v starts as e0 row

    float tA[UNROLL * 4], tB[UNROLL * 4];
    float dA[UNROLL],     dB[UNROLL];

    auto dload = [&](float (&dst)[UNROLL], int k) {
        const float4* p = (const float4*)(dp + k * UNROLL);
        #pragma unroll
        for (int j = 0; j < UNROLL / 4; j++) {
            float4 t = p[j];
            dst[j*4+0] = t.x; dst[j*4+1] = t.y; dst[j*4+2] = t.z; dst[j*4+3] = t.w;
        }
    };
    auto tload = [&](float (&tb)[UNROLL * 4], const float (&db)[UNROLL], int k) {
        const float* bp = tp + (size_t)k * UNROLL * 32 + r * 2;
        #pragma unroll
        for (int j = 0; j < UNROLL; j++) {
            // selected P-slice: element (l*8 + r*2 + sel), l via imm offsets
            const float* q = bp + j * 32 + ((db[j] == 1.0f) ? 0 : 1);
            tb[j*4+0] = q[0];  tb[j*4+1] = q[8];
            tb[j*4+2] = q[16]; tb[j*4+3] = q[24];
        }
    };
    auto comp = [&](const float (&tb)[UNROLL * 4]) {
        #pragma unroll
        for (int j = 0; j < UNROLL; j++) {
            float acc = qb<0>(v) * tb[j*4+0];
            acc = fmaf(qb<1>(v), tb[j*4+1], acc);
            acc = fmaf(qb<2>(v), tb[j*4+2], acc);
            v   = fmaf(qb<3>(v), tb[j*4+3], acc);
        }
    };

    if (nfull > 0) {
        const int last = nfull - 1;
        dload(dA, 0);
        dload(dB, (1 < last) ? 1 : last);
        tload(tA, dA, 0);
        for (int k = 0; k < nfull; k += 2) {
            dload(dA, (k + 2 < last) ? k + 2 : last);
            const bool has1 = (k + 1 < nfull);
            if (has1) tload(tB, dB, k + 1);
            comp(tA);
            if (has1) {
                dload(dB, (k + 3 < last) ? k + 3 : last);
                if (k + 2 < nfull) tload(tA, dA, k + 2);
                comp(tB);
            }
        }
    }
    // tail steps (< UNROLL)
    for (int m = nfull * UNROLL; m < steps; m++) {
        float d = dp[m];
        const float* q = tp + (size_t)m * 32 + r * 2 + ((d == 1.0f) ? 0 : 1);
        float acc = qb<0>(v) * q[0];
        acc = fmaf(qb<1>(v), q[8],  acc);
        acc = fmaf(qb<2>(v), q[16], acc);
        v   = fmaf(qb<3>(v), q[24], acc);
    }

    // epilogue: logits, log-softmax over p, select by data bit at position n+1
    const int pos = n + 1;
    const float* dg = diag + pos * 8 + r * 2;
    float o0 = v * dg[0];
    float o1 = v * dg[1];
    o0 += qperm<0xB1>(o0); o0 += qperm<0x4E>(o0);   // quad sum over r
    o1 += qperm<0xB1>(o1); o1 += qperm<0x4E>(o1);
    float mx  = fmaxf(o0, o1);
    float lse = mx + __logf(__expf(o0 - mx) + __expf(o1 - mx));
    float dsel = dp[pos];
    if (lane < 32 && r == 0)
        ws[bx * BATCH + b] = ((dsel == 1.0f) ? o0 : o1) - lse;
}

__global__ __launch_bounds__(64) void amps_reduce(const float* __restrict__ ws,
                                                  float* __restrict__ out)
{
    const int t = threadIdx.x;            // 64 threads
    const int b = t & 7, g = t >> 3;
    float s = 0.0f;
    #pragma unroll 4
    for (int k = g; k < NPOS; k += 8) s += ws[k * BATCH + b];
    s += __shfl_down(s, 32);
    s += __shfl_down(s, 16);
    s += __shfl_down(s, 8);
    if (t < 8) out[t] = s;
}

extern "C" void kernel_launch(void* const* d_in, const int* in_sizes, int n_in,
                              void* d_out, int out_size, void* d_ws, size_t ws_size,
                              hipStream_t stream)
{
    const float* data = (const float*)d_in[0];   // (8, 1024)
    const float* tri  = (const float*)d_in[1];   // (523776, 4, 4, 2)
    const float* diag = (const float*)d_in[2];   // (1024, 4, 2)
    float* ws  = (float*)d_ws;                   // needs 1024*8*4 = 32 KB
    float* out = (float*)d_out;                  // 8 floats

    amps_chain<<<dim3(NPOS), dim3(64), 0, stream>>>(data, tri, diag, ws);
    amps_reduce<<<dim3(1), dim3(64), 0, stream>>>(ws, out);
}